// Round 7
// baseline (803.675 us; speedup 1.0000x reference)
//
#include <hip/hip_runtime.h>
#include <hip/hip_bf16.h>
#include <math.h>

#define HD 2048
#define ID 1024
#define NE 32
#define TOPK 4
#define NTOK 4096
#define NSLOT (NTOK*TOPK)

typedef __attribute__((ext_vector_type(4))) float f32x4;
typedef __attribute__((ext_vector_type(8))) short bf16x8;
typedef unsigned short u16;
typedef unsigned int u32;

union U32x4BF { uint4 u; bf16x8 h; };

static __device__ __forceinline__ u16 f2bf(float f) {
  union { float f; u32 u; } v; v.f = f;
  u32 r = v.u + 0x7fffu + ((v.u >> 16) & 1u);
  return (u16)(r >> 16);
}

static __device__ __forceinline__ u32 cvtpk(float lo, float hi) {
  u32 r;
  asm("v_cvt_pk_bf16_f32 %0, %1, %2" : "=v"(r) : "v"(lo), "v"(hi));
  return r;
}

static __device__ __forceinline__ void barrier_lgkm() {
  asm volatile("s_waitcnt lgkmcnt(0)" ::: "memory");
  __builtin_amdgcn_s_barrier();
}

static __device__ __forceinline__ void loadB4(const float* bsrc, int ldb, float4* bv) {
  #pragma unroll
  for (int i = 0; i < 4; ++i) bv[i] = *(const float4*)(bsrc + (size_t)i*ldb);
}

static __device__ __forceinline__ void packB(u16* blbuf, int sc4, int bq4, const float4* bv) {
  const float* f0 = (const float*)&bv[0];
  const float* f1 = (const float*)&bv[1];
  const float* f2 = (const float*)&bv[2];
  const float* f3 = (const float*)&bv[3];
  #pragma unroll
  for (int j = 0; j < 4; ++j) {
    uint2 wv; wv.x = cvtpk(f0[j], f1[j]); wv.y = cvtpk(f2[j], f3[j]);
    *(uint2*)&blbuf[(sc4+j)*32 + bq4] = wv;
  }
}

// ---------------- RMSNorm -> bf16 ----------------
__global__ __launch_bounds__(256) void k_rmsnorm(const float* __restrict__ x,
                                                 const float* __restrict__ w,
                                                 u16* __restrict__ xn) {
  int t = blockIdx.x, tid = threadIdx.x;
  const float* row = x + (size_t)t * HD;
  float4 v0 = ((const float4*)row)[tid*2+0];
  float4 v1 = ((const float4*)row)[tid*2+1];
  float ss = v0.x*v0.x+v0.y*v0.y+v0.z*v0.z+v0.w*v0.w
           + v1.x*v1.x+v1.y*v1.y+v1.z*v1.z+v1.w*v1.w;
  #pragma unroll
  for (int d=1; d<64; d<<=1) ss += __shfl_xor(ss, d);
  __shared__ float red[4];
  if ((tid&63)==0) red[tid>>6] = ss;
  __syncthreads();
  float rs = rsqrtf((red[0]+red[1]+red[2]+red[3]) * (1.0f/HD) + 1e-6f);
  const float* wp = w + tid*8;
  float a[8] = {v0.x,v0.y,v0.z,v0.w,v1.x,v1.y,v1.z,v1.w};
  uint4 o;
  o.x = (u32)f2bf(a[0]*rs*wp[0]) | ((u32)f2bf(a[1]*rs*wp[1])<<16);
  o.y = (u32)f2bf(a[2]*rs*wp[2]) | ((u32)f2bf(a[3]*rs*wp[3])<<16);
  o.z = (u32)f2bf(a[4]*rs*wp[4]) | ((u32)f2bf(a[5]*rs*wp[5])<<16);
  o.w = (u32)f2bf(a[6]*rs*wp[6]) | ((u32)f2bf(a[7]*rs*wp[7])<<16);
  ((uint4*)xn)[(size_t)t*(HD/8) + tid] = o;
}

// ---------------- Gate ----------------
__global__ __launch_bounds__(256) void k_gate(const float* __restrict__ x,
                                              const float* __restrict__ w,
                                              const float* __restrict__ gw,
                                              int* __restrict__ topk_id,
                                              float* __restrict__ topk_w,
                                              int* __restrict__ counts) {
  __shared__ float xs[HD];
  __shared__ float red[4];
  __shared__ float logits[NE];
  int t = blockIdx.x, tid = threadIdx.x;
  const float* row = x + (size_t)t*HD;
  float4 v0 = ((const float4*)row)[tid*2+0];
  float4 v1 = ((const float4*)row)[tid*2+1];
  float ss = v0.x*v0.x+v0.y*v0.y+v0.z*v0.z+v0.w*v0.w
           + v1.x*v1.x+v1.y*v1.y+v1.z*v1.z+v1.w*v1.w;
  #pragma unroll
  for (int d=1; d<64; d<<=1) ss += __shfl_xor(ss, d);
  if ((tid&63)==0) red[tid>>6] = ss;
  __syncthreads();
  float rs = 1.0f / sqrtf((red[0]+red[1]+red[2]+red[3]) * (1.0f/HD) + 1e-6f);
  const float* wp = w + tid*8;
  float a[8] = {v0.x,v0.y,v0.z,v0.w,v1.x,v1.y,v1.z,v1.w};
  #pragma unroll
  for (int j=0;j<8;++j) xs[tid*8+j] = a[j]*rs*wp[j];
  __syncthreads();
  int wave = tid>>6, lane = tid&63;
  for (int ei=0; ei<8; ++ei) {
    int e = wave*8 + ei;
    const float* g = gw + (size_t)e*HD;
    float s = 0.f;
    #pragma unroll
    for (int j=0;j<HD/64;++j) s += xs[lane + j*64] * g[lane + j*64];
    #pragma unroll
    for (int d=1; d<64; d<<=1) s += __shfl_xor(s, d);
    if (lane==0) logits[e] = s;
  }
  __syncthreads();
  if (tid==0) {
    float best[TOPK]; int bid[TOPK]; unsigned used = 0;
    for (int k2=0;k2<TOPK;++k2) {
      float bv = -1e30f; int bi = 0;
      for (int i2=0;i2<NE;++i2)
        if (!((used>>i2)&1u) && logits[i2] > bv) { bv = logits[i2]; bi = i2; }
      used |= 1u<<bi; best[k2] = bv; bid[k2] = bi;
    }
    float mx = best[0], sum = 0.f, wv[TOPK];
    for (int k2=0;k2<TOPK;++k2) { wv[k2] = expf(best[k2]-mx); sum += wv[k2]; }
    float inv = 1.f/sum;
    for (int k2=0;k2<TOPK;++k2) {
      topk_id[t*TOPK+k2] = bid[k2];
      topk_w[t*TOPK+k2] = wv[k2]*inv;
      atomicAdd(&counts[bid[k2]], 1);
    }
  }
}

__global__ void k_zero(int* counts, int* cursors) {
  int i = threadIdx.x;
  if (i < NE) { counts[i] = 0; cursors[i] = 0; }
}

__global__ void k_scan(const int* __restrict__ counts, int* __restrict__ starts) {
  if (threadIdx.x==0 && blockIdx.x==0) {
    int acc = 0;
    for (int e=0;e<NE;++e) { starts[e] = acc; acc += counts[e]; }
  }
}

__global__ __launch_bounds__(256) void k_dispatch(const int* __restrict__ topk_id,
                                                  const float* __restrict__ topk_w,
                                                  const int* __restrict__ starts,
                                                  int* __restrict__ cursors,
                                                  int* __restrict__ slot_tok,
                                                  float* __restrict__ slot_w) {
  int i = blockIdx.x*256 + threadIdx.x;
  int e = topk_id[i];
  int p = atomicAdd(&cursors[e], 1);
  int slot = starts[e] + p;
  slot_tok[slot] = i >> 2;
  slot_w[slot] = topk_w[i];
}

// ============ GEMM up: 2-deep reg pipeline, LDS dbuf, 1 barrier/step ============
template<bool INDEXED>
__global__ __launch_bounds__(256) void k_gemm_up(
    const u16* __restrict__ A, int lda, int kiter,
    const float* __restrict__ Bg, const float* __restrict__ Bu,
    size_t bstride, int ldb,
    const int* __restrict__ counts, const int* __restrict__ starts,
    const int* __restrict__ slot_tok,
    u16* __restrict__ actOut) {
  __shared__ u16 Al[2][4096];
  __shared__ u16 Bl[2][4096];
  __shared__ int rowL[128];
  int t = threadIdx.x;
  int n0 = blockIdx.x * 64;
  int m0 = blockIdx.y * 128;
  int e  = blockIdx.z;
  int M, rowbase;
  if (INDEXED) { M = counts[e]; rowbase = starts[e]; if (m0 >= M) return; }
  else { M = NTOK; rowbase = 0; }
  if (t < 128) {
    int m = m0 + t;
    rowL[t] = INDEXED ? slot_tok[rowbase + (m < M ? m : M-1)] : m;
  }
  __syncthreads();
  int r0i = t>>2, r1i = r0i + 64;
  int segA = ((t&3) ^ ((r0i>>1)&3)) << 3;
  const u16* srcA0 = A + (size_t)rowL[r0i]*lda + segA;
  const u16* srcA1 = A + (size_t)rowL[r1i]*lda + segA;
  int sc4 = (t&31)*4;
  int kb  = t>>5;
  int isup = (sc4>>4)&1;
  int srccol = n0 + ((sc4>>5)<<4) + (sc4&15);
  const float* bsrc = (isup ? Bu : Bg) + (INDEXED ? (size_t)e*bstride : 0)
                    + (size_t)(kb*4)*ldb + srccol;
  int bq4 = (kb ^ (t&7))*4;

  int lane = t&63, wave = t>>6, wr = wave>>1, wc = wave&1;
  int l15 = lane&15, l4 = lane>>4;
  int aoff[4], b0off[4], b1off[4];
  #pragma unroll
  for (int f=0; f<4; ++f) {
    int r = wr*64 + f*16 + l15;
    aoff[f] = r*32 + ((l4 ^ ((r>>1)&3))<<3);
    int c = wc*64 + f*16 + l15;
    int g = (c>>2)&7;
    b0off[f] = c*32 + (((2*l4)   ^ g)<<2);
    b1off[f] = c*32 + (((2*l4+1) ^ g)<<2);
  }
  f32x4 acc[4][4];
  #pragma unroll
  for (int fm=0;fm<4;++fm)
    #pragma unroll
    for (int fn=0;fn<4;++fn)
      acc[fm][fn] = (f32x4){0.f,0.f,0.f,0.f};

  // prologue: slotA = tile0, slotB = tile1; write tile0 -> buf0
  uint4 aA0 = *(const uint4*)srcA0, aA1 = *(const uint4*)srcA1;
  float4 bvA[4]; loadB4(bsrc, ldb, bvA);
  srcA0 += 32; srcA1 += 32; bsrc += (size_t)32*ldb;
  uint4 aB0 = *(const uint4*)srcA0, aB1 = *(const uint4*)srcA1;
  float4 bvB[4]; loadB4(bsrc, ldb, bvB);
  srcA0 += 32; srcA1 += 32; bsrc += (size_t)32*ldb;
  *(uint4*)&Al[0][t*8] = aA0;
  *(uint4*)&Al[0][2048 + t*8] = aA1;
  packB(Bl[0], sc4, bq4, bvA);
  barrier_lgkm();

  for (int kt = 0; kt < kiter; kt += 2) {
    // even phase: compute buf0 (tile kt); write slotB(tile kt+1)->buf1; load slotA=tile kt+2
    if (kt+2 < kiter) {
      aA0 = *(const uint4*)srcA0; aA1 = *(const uint4*)srcA1;
      loadB4(bsrc, ldb, bvA);
      srcA0 += 32; srcA1 += 32; bsrc += (size_t)32*ldb;
    }
    {
      bf16x8 af[4], bfr[4];
      #pragma unroll
      for (int f=0; f<4; ++f) af[f] = *(const bf16x8*)&Al[0][aoff[f]];
      #pragma unroll
      for (int f=0; f<4; ++f) {
        uint2 lo = *(const uint2*)&Bl[0][b0off[f]];
        uint2 hi = *(const uint2*)&Bl[0][b1off[f]];
        U32x4BF ub; ub.u = make_uint4(lo.x, lo.y, hi.x, hi.y);
        bfr[f] = ub.h;
      }
      #pragma unroll
      for (int fm=0; fm<4; ++fm)
        #pragma unroll
        for (int fn=0; fn<4; ++fn)
          acc[fm][fn] = __builtin_amdgcn_mfma_f32_16x16x32_bf16(af[fm], bfr[fn], acc[fm][fn], 0,0,0);
    }
    *(uint4*)&Al[1][t*8] = aB0;            // waits only slotB's loads (vmcnt(6))
    *(uint4*)&Al[1][2048 + t*8] = aB1;
    packB(Bl[1], sc4, bq4, bvB);
    barrier_lgkm();
    // odd phase: compute buf1 (tile kt+1); write slotA(tile kt+2)->buf0; load slotB=tile kt+3
    if (kt+3 < kiter) {
      aB0 = *(const uint4*)srcA0; aB1 = *(const uint4*)srcA1;
      loadB4(bsrc, ldb, bvB);
      srcA0 += 32; srcA1 += 32; bsrc += (size_t)32*ldb;
    }
    {
      bf16x8 af[4], bfr[4];
      #pragma unroll
      for (int f=0; f<4; ++f) af[f] = *(const bf16x8*)&Al[1][aoff[f]];
      #pragma unroll
      for (int f=0; f<4; ++f) {
        uint2 lo = *(const uint2*)&Bl[1][b0off[f]];
        uint2 hi = *(const uint2*)&Bl[1][b1off[f]];
        U32x4BF ub; ub.u = make_uint4(lo.x, lo.y, hi.x, hi.y);
        bfr[f] = ub.h;
      }
      #pragma unroll
      for (int fm=0; fm<4; ++fm)
        #pragma unroll
        for (int fn=0; fn<4; ++fn)
          acc[fm][fn] = __builtin_amdgcn_mfma_f32_16x16x32_bf16(af[fm], bfr[fn], acc[fm][fn], 0,0,0);
    }
    if (kt+2 < kiter) {
      *(uint4*)&Al[0][t*8] = aA0;
      *(uint4*)&Al[0][2048 + t*8] = aA1;
      packB(Bl[0], sc4, bq4, bvA);
    }
    barrier_lgkm();
  }
  // epilogue: SwiGLU on (gate,up) fragment pairs
  #pragma unroll
  for (int fm=0; fm<4; ++fm) {
    #pragma unroll
    for (int fq=0; fq<2; ++fq) {
      f32x4 g = acc[fm][2*fq], u = acc[fm][2*fq+1];
      int col = n0 + (wc*2+fq)*16 + l15;
      #pragma unroll
      for (int r=0;r<4;++r) {
        int mloc = wr*64 + fm*16 + l4*4 + r;
        int m = m0 + mloc;
        if (m < M) {
          float gv = g[r];
          float av = gv / (1.f + expf(-gv)) * u[r];
          actOut[(size_t)(rowbase+m)*ID + col] = f2bf(av);
        }
      }
    }
  }
}

// ============ GEMM down: 2-deep reg pipeline ============
template<bool INDEXED>
__global__ __launch_bounds__(256) void k_gemm_down(
    const u16* __restrict__ A, int lda, int kiter,
    const float* __restrict__ B, size_t bstride, int ldb,
    const int* __restrict__ counts, const int* __restrict__ starts,
    const int* __restrict__ slot_tok, const float* __restrict__ slot_w,
    const float* __restrict__ resid,
    float* __restrict__ out) {
  __shared__ u16 Al[2][4096];
  __shared__ u16 Bl[2][4096];
  __shared__ int tokL[128];
  __shared__ float wL[128];
  int t = threadIdx.x;
  int n0 = blockIdx.x * 128;
  int m0 = blockIdx.y * 128;
  int e  = blockIdx.z;
  int M, rowbase;
  if (INDEXED) { M = counts[e]; rowbase = starts[e]; if (m0 >= M) return; }
  else { M = NTOK; rowbase = 0; }
  if (INDEXED && t < 128) {
    int m = m0 + t;
    tokL[t] = (m<M) ? slot_tok[rowbase+m] : 0;
    wL[t]   = (m<M) ? slot_w[rowbase+m]  : 0.f;
  }
  if (INDEXED) __syncthreads();
  int r0i = t>>2, r1i = r0i + 64;
  int segA = ((t&3) ^ ((r0i>>1)&3)) << 3;
  int am0 = m0 + r0i, am1 = m0 + r1i;
  const u16* srcA0 = A + (size_t)(rowbase + (am0 < M ? am0 : M-1))*lda + segA;
  const u16* srcA1 = A + (size_t)(rowbase + (am1 < M ? am1 : M-1))*lda + segA;
  int sc4 = (t&31)*4;
  int kb  = t>>5;
  const float* bsrc = B + (INDEXED ? (size_t)e*bstride : 0)
                    + (size_t)(kb*4)*ldb + (n0 + sc4);
  int bq4 = (kb ^ (t&7))*4;

  int lane = t&63, wave = t>>6, wr = wave>>1, wc = wave&1;
  int l15 = lane&15, l4 = lane>>4;
  int aoff[4], b0off[4], b1off[4];
  #pragma unroll
  for (int f=0; f<4; ++f) {
    int r = wr*64 + f*16 + l15;
    aoff[f] = r*32 + ((l4 ^ ((r>>1)&3))<<3);
    int c = wc*64 + f*16 + l15;
    int g = (c>>2)&7;
    b0off[f] = c*32 + (((2*l4)   ^ g)<<2);
    b1off[f] = c*32 + (((2*l4+1) ^ g)<<2);
  }
  f32x4 acc[4][4];
  #pragma unroll
  for (int fm=0;fm<4;++fm)
    #pragma unroll
    for (int fn=0;fn<4;++fn)
      acc[fm][fn] = (f32x4){0.f,0.f,0.f,0.f};

  uint4 aA0 = *(const uint4*)srcA0, aA1 = *(const uint4*)srcA1;
  float4 bvA[4]; loadB4(bsrc, ldb, bvA);
  srcA0 += 32; srcA1 += 32; bsrc += (size_t)32*ldb;
  uint4 aB0 = *(const uint4*)srcA0, aB1 = *(const uint4*)srcA1;
  float4 bvB[4]; loadB4(bsrc, ldb, bvB);
  srcA0 += 32; srcA1 += 32; bsrc += (size_t)32*ldb;
  *(uint4*)&Al[0][t*8] = aA0;
  *(uint4*)&Al[0][2048 + t*8] = aA1;
  packB(Bl[0], sc4, bq4, bvA);
  barrier_lgkm();

  for (int kt = 0; kt < kiter; kt += 2) {
    if (kt+2 < kiter) {
      aA0 = *(const uint4*)srcA0; aA1 = *(const uint4*)srcA1;
      loadB4(bsrc, ldb, bvA);
      srcA0 += 32; srcA1 += 32; bsrc += (size_t)32*ldb;
    }
    {
      bf16x8 af[4], bfr[4];
      #pragma unroll
      for (int f=0; f<4; ++f) af[f] = *(const bf16x8*)&Al[0][aoff[f]];
      #pragma unroll
      for (int f=0; f<4; ++f) {
        uint2 lo = *(const uint2*)&Bl[0][b0off[f]];
        uint2 hi = *(const uint2*)&Bl[0][b1off[f]];
        U32x4BF ub; ub.u = make_uint4(lo.x, lo.y, hi.x, hi.y);
        bfr[f] = ub.h;
      }
      #pragma unroll
      for (int fm=0; fm<4; ++fm)
        #pragma unroll
        for (int fn=0; fn<4; ++fn)
          acc[fm][fn] = __builtin_amdgcn_mfma_f32_16x16x32_bf16(af[fm], bfr[fn], acc[fm][fn], 0,0,0);
    }
    *(uint4*)&Al[1][t*8] = aB0;
    *(uint4*)&Al[1][2048 + t*8] = aB1;
    packB(Bl[1], sc4, bq4, bvB);
    barrier_lgkm();
    if (kt+3 < kiter) {
      aB0 = *(const uint4*)srcA0; aB1 = *(const uint4*)srcA1;
      loadB4(bsrc, ldb, bvB);
      srcA0 += 32; srcA1 += 32; bsrc += (size_t)32*ldb;
    }
    {
      bf16x8 af[4], bfr[4];
      #pragma unroll
      for (int f=0; f<4; ++f) af[f] = *(const bf16x8*)&Al[1][aoff[f]];
      #pragma unroll
      for (int f=0; f<4; ++f) {
        uint2 lo = *(const uint2*)&Bl[1][b0off[f]];
        uint2 hi = *(const uint2*)&Bl[1][b1off[f]];
        U32x4BF ub; ub.u = make_uint4(lo.x, lo.y, hi.x, hi.y);
        bfr[f] = ub.h;
      }
      #pragma unroll
      for (int fm=0; fm<4; ++fm)
        #pragma unroll
        for (int fn=0; fn<4; ++fn)
          acc[fm][fn] = __builtin_amdgcn_mfma_f32_16x16x32_bf16(af[fm], bfr[fn], acc[fm][fn], 0,0,0);
    }
    if (kt+2 < kiter) {
      *(uint4*)&Al[0][t*8] = aA0;
      *(uint4*)&Al[0][2048 + t*8] = aA1;
      packB(Bl[0], sc4, bq4, bvA);
    }
    barrier_lgkm();
  }
  #pragma unroll
  for (int fm=0; fm<4; ++fm) {
    #pragma unroll
    for (int fn=0; fn<4; ++fn) {
      f32x4 v = acc[fm][fn];
      int col = n0 + wc*64 + fn*16 + l15;
      #pragma unroll
      for (int r=0;r<4;++r) {
        int mloc = wr*64 + fm*16 + l4*4 + r;
        int m = m0 + mloc;
        if (m < M) {
          if (INDEXED) {
            atomicAdd(&out[(size_t)tokL[mloc]*HD + col], v[r]*wL[mloc]);
          } else {
            size_t o = (size_t)m*HD + col;
            out[o] = resid[o] + v[r];
          }
        }
      }
    }
  }
}

extern "C" void kernel_launch(void* const* d_in, const int* in_sizes, int n_in,
                              void* d_out, int out_size, void* d_ws, size_t ws_size,
                              hipStream_t stream) {
  const float* x    = (const float*)d_in[0];
  const float* nw   = (const float*)d_in[1];
  const float* gw   = (const float*)d_in[2];
  const float* w13  = (const float*)d_in[3];
  const float* w2   = (const float*)d_in[4];
  const float* sgw  = (const float*)d_in[5];
  const float* suw  = (const float*)d_in[6];
  const float* sdw  = (const float*)d_in[7];
  float* out = (float*)d_out;

  char* p = (char*)d_ws;
  u16* xn   = (u16*)p;  p += (size_t)NTOK*HD*2;
  u16* act  = (u16*)p;  p += (size_t)NSLOT*ID*2;
  u16* sact = (u16*)p;  p += (size_t)NTOK*ID*2;
  int*   topk_id  = (int*)p;   p += (size_t)NTOK*TOPK*4;
  float* topk_w   = (float*)p; p += (size_t)NTOK*TOPK*4;
  int*   slot_tok = (int*)p;   p += (size_t)NSLOT*4;
  float* slot_w   = (float*)p; p += (size_t)NSLOT*4;
  int*   counts   = (int*)p;   p += 64*4;
  int*   cursors  = (int*)p;   p += 64*4;
  int*   starts   = (int*)p;   p += 64*4;

  k_zero<<<1, 64, 0, stream>>>(counts, cursors);
  k_rmsnorm<<<NTOK, 256, 0, stream>>>(x, nw, xn);
  k_gate<<<NTOK, 256, 0, stream>>>(x, nw, gw, topk_id, topk_w, counts);
  k_scan<<<1, 1, 0, stream>>>(counts, starts);
  k_dispatch<<<NSLOT/256, 256, 0, stream>>>(topk_id, topk_w, starts, cursors, slot_tok, slot_w);

  // routed up-proj + swiglu (B = w13 fp32, gate cols [0,I), up cols [I,2I))
  k_gemm_up<true><<<dim3(ID/64, 8, NE), 256, 0, stream>>>(
      xn, HD, HD/32, w13, w13 + ID, (size_t)HD*2*ID, 2*ID,
      counts, starts, slot_tok, act);
  // shared up-proj + swiglu
  k_gemm_up<false><<<dim3(ID/64, NTOK/128, 1), 256, 0, stream>>>(
      xn, HD, HD/32, sgw, suw, 0, ID, nullptr, nullptr, nullptr, sact);
  // shared down-proj: out = residual + shared
  k_gemm_down<false><<<dim3(HD/128, NTOK/128, 1), 256, 0, stream>>>(
      sact, ID, ID/32, sdw, 0, HD, nullptr, nullptr, nullptr, nullptr, x, out);
  // routed down-proj: atomic weighted scatter-add into out
  k_gemm_down<true><<<dim3(HD/128, 8, NE), 256, 0, stream>>>(
      act, ID, ID/32, w2, (size_t)ID*HD, HD, counts, starts, slot_tok, slot_w, nullptr, out);
}